// Round 2
// baseline (229.095 us; speedup 1.0000x reference)
//
#include <hip/hip_runtime.h>

typedef unsigned short u16;
typedef __bf16 bf16;
typedef bf16 bf16x8 __attribute__((ext_vector_type(8)));
typedef float f32x4 __attribute__((ext_vector_type(4)));
typedef u16 u16x4 __attribute__((ext_vector_type(4)));
typedef u16 u16x8 __attribute__((ext_vector_type(8)));

#define MROWS 8192      // B*S
#define EDIM 768
#define NQKV 2304       // 3*E
#define NHEAD 12
#define DH 64
#define SEQ 1024
#define BATCH 8
#define BH 96           // BATCH*NHEAD
#define BHSD (BH * SEQ * DH)
#define KIT64 (EDIM / 64)   // 12

#if __has_builtin(__builtin_amdgcn_exp2f)
#define EXP2(x) __builtin_amdgcn_exp2f(x)
#else
#define EXP2(x) exp2f(x)
#endif

// float -> bf16 (native cvt on gfx950, RNE)
__device__ __forceinline__ u16 f2bf(float f) {
  bf16 b = (bf16)f;
  return __builtin_bit_cast(u16, b);
}

// async global->LDS, 16B per lane. LDS dest must be wave-uniform base + lane*16.
__device__ __forceinline__ void gload_lds16(const u16* g, u16* l) {
  __builtin_amdgcn_global_load_lds(
      (const __attribute__((address_space(1))) void*)g,
      (__attribute__((address_space(3))) void*)l, 16, 0, 0);
}

// ---------------- prep kernels ----------------

__global__ void cvt_x(const float* __restrict__ x, u16* __restrict__ xb, int n) {
  int i = (blockIdx.x * blockDim.x + threadIdx.x) * 4;
  if (i >= n) return;
  float4 v = *(const float4*)(x + i);
  u16x4 o;
  o[0] = f2bf(v.x); o[1] = f2bf(v.y); o[2] = f2bf(v.z); o[3] = f2bf(v.w);
  *(u16x4*)(xb + i) = o;
}

// LDS tile-transpose pack. Blocks 0..431: Wt tiles; 432..575: Wot tiles.
// Wt[n][e], n=region*768+h*64+d, equals W_region[h][e][d]. Wot[n][e]=Wo[e][n].
__global__ __launch_bounds__(256) void pack_w(
    const float* __restrict__ Wq, const float* __restrict__ Wk,
    const float* __restrict__ Wv, const float* __restrict__ Wo,
    u16* __restrict__ Wt, u16* __restrict__ Wot) {
  __shared__ float T[64][65];
  int bid = blockIdx.x;
  int tid = threadIdx.x;
  int c = tid & 63, r4 = tid >> 6;    // 4 rows per pass, 16 passes
  if (bid < 432) {
    int region = bid / 144, rem = bid - region * 144;
    int h = rem / 12, e0 = (rem - h * 12) * 64;
    const float* W = region == 0 ? Wq : (region == 1 ? Wk : Wv);
    for (int p = 0; p < 16; p++) {
      int er = r4 + p * 4;
      T[er][c] = W[(size_t)(h * EDIM + e0 + er) * DH + c];   // coalesced read (d=c)
    }
    __syncthreads();
    int nbase = region * EDIM + h * 64;
    for (int p = 0; p < 16; p++) {
      int dr = r4 + p * 4;
      Wt[(size_t)(nbase + dr) * EDIM + e0 + c] = f2bf(T[c][dr]);  // coalesced write (e=c)
    }
  } else {
    bid -= 432;
    int n0 = (bid / 12) * 64, e0 = (bid - (bid / 12) * 12) * 64;
    for (int p = 0; p < 16; p++) {
      int er = r4 + p * 4;
      T[er][c] = Wo[(size_t)(e0 + er) * EDIM + n0 + c];      // coalesced read (n=c)
    }
    __syncthreads();
    for (int p = 0; p < 16; p++) {
      int dr = r4 + p * 4;
      Wot[(size_t)(n0 + dr) * EDIM + e0 + c] = f2bf(T[c][dr]);
    }
  }
}

// ---------------- GEMM core: 128x128 tile, BK=64, global_load_lds staging ----------
// XOR swizzle (zero bank conflicts measured): element [row][c*8+j] lives at
// row*64 + ((c ^ (row&7))*8 + j). global_load_lds writes LDS LINEARLY
// (wave base + lane*16), so the swizzle is applied on the GLOBAL SOURCE
// address (rule #21: linear dest + inverse-swizzled source + swizzled read).
__device__ __forceinline__ void gemm_core64(
    const u16* __restrict__ A, const u16* __restrict__ Bt,
    u16* As, u16* Bs,                 // each 128*64 elements (16 KB)
    int m0, int n0, int tid, f32x4 acc[4][4]) {
  int wv = __builtin_amdgcn_readfirstlane(tid >> 6);
  int lane = tid & 63, quad = lane >> 4, l16 = lane & 15;
  int wm = (wv & 1) * 64, wn = (wv >> 1) * 64;
  int lr = lane >> 3, cpos = lane & 7;       // 8 rows x 8 16B-chunks per wave-instr
  int swcol = (cpos ^ lr) * 8;               // inverse-swizzled source column
  const u16* Ag = A + (size_t)(m0 + wv * 32 + lr) * EDIM + swcol;
  const u16* Bg = Bt + (size_t)(n0 + wv * 32 + lr) * EDIM + swcol;
  u16* Asl = As + (wv * 32 + lr) * 64 + cpos * 8;   // == wave base + lane*16B
  u16* Bsl = Bs + (wv * 32 + lr) * 64 + cpos * 8;

  for (int k = 0; k < KIT64; k++) {
    __syncthreads();                 // previous iter's ds_reads complete before overwrite
    const u16* ak = Ag + k * 64;
    const u16* bk = Bg + k * 64;
#pragma unroll
    for (int q = 0; q < 4; q++) {    // q: 8-row groups; wave covers rows wv*32..wv*32+31
      gload_lds16(ak + q * 8 * EDIM, Asl + q * 512);
      gload_lds16(bk + q * 8 * EDIM, Bsl + q * 512);
    }
    __syncthreads();                 // compiler drains vmcnt(0) here: tile ready
#pragma unroll
    for (int kh = 0; kh < 2; kh++) {
      bf16x8 af[4], bfr[4];
      for (int i = 0; i < 4; i++) {
        int row = wm + i * 16 + l16;
        af[i] = *(const bf16x8*)(As + row * 64 + (((kh * 4 + quad) ^ (row & 7))) * 8);
      }
      for (int j = 0; j < 4; j++) {
        int row = wn + j * 16 + l16;
        bfr[j] = *(const bf16x8*)(Bs + row * 64 + (((kh * 4 + quad) ^ (row & 7))) * 8);
      }
      for (int i = 0; i < 4; i++)
        for (int j = 0; j < 4; j++)
          acc[i][j] = __builtin_amdgcn_mfma_f32_16x16x32_bf16(af[i], bfr[j], acc[i][j], 0, 0, 0);
    }
  }
}

// ---------------- GEMM 1: QKV projection ----------------
// XCD remap: lin%8 = XCD (round-robin dispatch). Each XCD owns 8 contiguous
// m-tiles x all 18 n-tiles -> its 1.5MB A-chunk stays hot in its private L2
// (was: A re-read 18x from L3, 227MB). Bijective: 64 mt = 8 xcd * 8.
__global__ __launch_bounds__(256, 4) void gemm_qkv(
    const u16* __restrict__ A, const u16* __restrict__ Bt,
    const float* __restrict__ bq, const float* __restrict__ bk, const float* __restrict__ bv,
    u16* __restrict__ qkv) {
  __shared__ __align__(16) u16 As[128 * 64];
  __shared__ __align__(16) u16 Bs[128 * 64];
  int tid = threadIdx.x;
  int wv = tid >> 6, lane = tid & 63, quad = lane >> 4, l16 = lane & 15;
  int wm = (wv & 1) * 64, wn = (wv >> 1) * 64;
  int lin = blockIdx.y * 64 + blockIdx.x;
  int xcd = lin & 7, r8 = lin >> 3;          // r8 in 0..143
  int m0 = (xcd * 8 + (r8 & 7)) * 128;
  int n0 = (r8 >> 3) * 128;                  // 0..17
  f32x4 acc[4][4] = {};
  gemm_core64(A, Bt, As, Bs, m0, n0, tid, acc);

  const float kQscale = 0.18033688011112042f; // (1/8) * log2(e)
  for (int i = 0; i < 4; i++) {
    int row0 = m0 + wm + i * 16 + quad * 4;
    for (int j = 0; j < 4; j++) {
      int n = n0 + wn + j * 16 + l16;
      int region = n / EDIM;
      int hd = n - region * EDIM;
      int h = hd >> 6, d = hd & 63;
      const float* bp = region == 0 ? bq : (region == 1 ? bk : bv);
      float bias = bp[hd];
      float scale = region == 0 ? kQscale : 1.0f;
      for (int r = 0; r < 4; r++) {
        int rr = row0 + r;
        int bb = rr >> 10, s = rr & 1023;
        float val = (acc[i][j][r] + bias) * scale;
        u16 bv16 = f2bf(val);
        int bhh = bb * NHEAD + h;
        if (region < 2) {
          qkv[(size_t)region * BHSD + ((size_t)bhh * SEQ + s) * DH + d] = bv16;
        } else {
          qkv[(size_t)2 * BHSD + ((size_t)bhh * DH + d) * SEQ + s] = bv16;
        }
      }
    }
  }
}

// ---------------- flash attention (no-max softmax, in-register row sums) -------------
// All LDS tiles XOR-swizzled: element [row][c*8+j] at row*64 + ((c^(row&7))*8+j)
// (same pattern as gemm_core64, measured 0 bank conflicts there; the old
// stride-72 layout measured 7.86M conflict cycles = ~22% of kernel time).
// Row sums accumulate in-register (psum) instead of the ones-column MFMA pair:
// -2 MFMA and -2 ds_read_b128 per wave per t-tile.
// XCD remap: each XCD runs one head's 16 q-tiles back-to-back (K/V 256KB hot in L2).
__global__ __launch_bounds__(256, 6) void attn_kernel(const u16* __restrict__ qkv, u16* __restrict__ attn) {
  int lin = blockIdx.y * 96 + blockIdx.x;
  int xcd = lin & 7, rr6 = lin >> 3;         // rr6 in 0..191
  int bh = xcd * 12 + (rr6 >> 4);            // 12 heads per XCD
  int qt = rr6 & 15;
  int b = bh / NHEAD, h = bh - b * NHEAD;
  const u16* Q  = qkv + (size_t)bh * SEQ * DH;
  const u16* K  = qkv + (size_t)(BH + bh) * SEQ * DH;
  const u16* VT = qkv + (size_t)(2 * BH + bh) * SEQ * DH;  // [64][1024]
  int tid = threadIdx.x, wave = tid >> 6, lane = tid & 63, quad = lane >> 4, l16 = lane & 15;
  int q_base = qt * 64 + wave * 16;

  __shared__ u16 Ks[64 * 64];       // [t][d] swizzled
  __shared__ u16 Vts[64 * 64];      // [d][t] swizzled
  __shared__ u16 Ps[4][16 * 64];    // per wave P tile [q][t] swizzled

  bf16x8 qf[2];
  for (int c = 0; c < 2; c++)
    qf[c] = *(const bf16x8*)(Q + (size_t)(q_base + l16) * DH + c * 32 + quad * 8);

  f32x4 o[4] = {};
  float psum[4] = {};   // per-lane partial row sums (cols l16+16k of rows quad*4+r)

  int tr = tid >> 3, cpos = tid & 7;          // staging: rows 0..31 (+32), 8 col-chunks
  int ssw = (cpos ^ (tr & 7)) * 8;            // swizzled chunk pos (same for tr, tr+32)
  u16* KsW0 = Ks + tr * 64 + ssw;
  u16* KsW1 = Ks + (tr + 32) * 64 + ssw;
  u16* VsW0 = Vts + tr * 64 + ssw;
  u16* VsW1 = Vts + (tr + 32) * 64 + ssw;
  int tc8 = cpos * 8;

  // prologue: prefetch tile 0 into registers
  u16x8 kv0 = *(const u16x8*)(K + (size_t)tr * DH + tc8);
  u16x8 kv1 = *(const u16x8*)(K + (size_t)(32 + tr) * DH + tc8);
  u16x8 vv0 = *(const u16x8*)(VT + (size_t)tr * SEQ + tc8);
  u16x8 vv1 = *(const u16x8*)(VT + (size_t)(32 + tr) * SEQ + tc8);

  for (int t0 = 0; t0 < SEQ; t0 += 64) {
    __syncthreads();
    *(u16x8*)KsW0 = kv0;
    *(u16x8*)KsW1 = kv1;
    *(u16x8*)VsW0 = vv0;
    *(u16x8*)VsW1 = vv1;
    __syncthreads();
    if (t0 + 64 < SEQ) {   // prefetch next tile during compute
      kv0 = *(const u16x8*)(K + (size_t)(t0 + 64 + tr) * DH + tc8);
      kv1 = *(const u16x8*)(K + (size_t)(t0 + 96 + tr) * DH + tc8);
      vv0 = *(const u16x8*)(VT + (size_t)tr * SEQ + t0 + 64 + tc8);
      vv1 = *(const u16x8*)(VT + (size_t)(32 + tr) * SEQ + t0 + 64 + tc8);
    }

    // scores + exp2 (logits in log2 domain via Q scale; statistically bounded, no max)
    float p[4][4];
    for (int tc = 0; tc < 4; tc++) {
      int krow = tc * 16 + l16, k7 = l16 & 7;
      bf16x8 kf0 = *(const bf16x8*)(Ks + krow * 64 + ((quad ^ k7) * 8));
      bf16x8 kf1 = *(const bf16x8*)(Ks + krow * 64 + (((4 + quad) ^ k7) * 8));
      f32x4 z = {};
      z = __builtin_amdgcn_mfma_f32_16x16x32_bf16(qf[0], kf0, z, 0, 0, 0);
      z = __builtin_amdgcn_mfma_f32_16x16x32_bf16(qf[1], kf1, z, 0, 0, 0);
      for (int r = 0; r < 4; r++) {
        p[tc][r] = EXP2(z[r]);
        psum[r] += p[tc][r];
      }
    }

    // P: C-layout -> A-layout via per-wave LDS round trip (swizzled)
    u16* P = Ps[wave];
    for (int tc = 0; tc < 4; tc++)
      for (int r = 0; r < 4; r++) {
        int prow = quad * 4 + r;
        int pc = tc * 2 + (l16 >> 3);
        P[prow * 64 + ((pc ^ (prow & 7)) * 8) + (l16 & 7)] = f2bf(p[tc][r]);
      }
    bf16x8 pf[2];
    for (int kc = 0; kc < 2; kc++)
      pf[kc] = *(const bf16x8*)(Ps[wave] + l16 * 64 + (((kc * 4 + quad) ^ (l16 & 7)) * 8));

    for (int n = 0; n < 4; n++) {
      int vrow = n * 16 + l16, v7 = l16 & 7;
      bf16x8 vf0 = *(const bf16x8*)(Vts + vrow * 64 + ((quad ^ v7) * 8));
      bf16x8 vf1 = *(const bf16x8*)(Vts + vrow * 64 + (((4 + quad) ^ v7) * 8));
      o[n] = __builtin_amdgcn_mfma_f32_16x16x32_bf16(pf[0], vf0, o[n], 0, 0, 0);
      o[n] = __builtin_amdgcn_mfma_f32_16x16x32_bf16(pf[1], vf1, o[n], 0, 0, 0);
    }
  }

  // finish row sums: reduce psum across the 16 lanes of each quad-group
  for (int m = 1; m < 16; m <<= 1)
    for (int r = 0; r < 4; r++)
      psum[r] += __shfl_xor(psum[r], m);

  // normalize + store to attn [8192][768] bf16, col = h*64 + d.
  for (int r = 0; r < 4; r++) {
    float inv = 1.0f / psum[r];
    int qrow = q_base + quad * 4 + r;
    size_t rowoff = (size_t)(b * SEQ + qrow) * EDIM + h * DH;
    for (int n = 0; n < 4; n++)
      attn[rowoff + n * 16 + l16] = f2bf(o[n][r] * inv);
  }
}

// ---------------- GEMM 3: output projection ----------------
__global__ __launch_bounds__(256, 4) void gemm_out(
    const u16* __restrict__ A, const u16* __restrict__ Bt,
    const float* __restrict__ bo, float* __restrict__ out) {
  __shared__ __align__(16) u16 As[128 * 64];
  __shared__ __align__(16) u16 Bs[128 * 64];
  int tid = threadIdx.x;
  int wv = tid >> 6, lane = tid & 63, quad = lane >> 4, l16 = lane & 15;
  int wm = (wv & 1) * 64, wn = (wv >> 1) * 64;
  int lin = blockIdx.y * 64 + blockIdx.x;
  int xcd = lin & 7, r8 = lin >> 3;          // r8 in 0..47
  int m0 = (xcd * 8 + (r8 & 7)) * 128;
  int n0 = (r8 >> 3) * 128;                  // 0..5
  f32x4 acc[4][4] = {};
  gemm_core64(A, Bt, As, Bs, m0, n0, tid, acc);

  for (int i = 0; i < 4; i++) {
    int row0 = m0 + wm + i * 16 + quad * 4;
    for (int j = 0; j < 4; j++) {
      int n = n0 + wn + j * 16 + l16;
      float bias = bo[n];
      for (int r = 0; r < 4; r++)
        out[(size_t)(row0 + r) * EDIM + n] = acc[i][j][r] + bias;
    }
  }
}

// ---------------- launch ----------------
extern "C" void kernel_launch(void* const* d_in, const int* in_sizes, int n_in,
                              void* d_out, int out_size, void* d_ws, size_t ws_size,
                              hipStream_t stream) {
  const float* x  = (const float*)d_in[0];
  const float* Wq = (const float*)d_in[1];
  const float* bq = (const float*)d_in[2];
  const float* Wk = (const float*)d_in[3];
  const float* bk = (const float*)d_in[4];
  const float* Wv = (const float*)d_in[5];
  const float* bv = (const float*)d_in[6];
  const float* Wo = (const float*)d_in[7];
  const float* bo = (const float*)d_in[8];
  float* out = (float*)d_out;
  char* ws = (char*)d_ws;

  u16* Xb   = (u16*)(ws);                      // 8192*768*2    = 12,582,912
  u16* Wt   = (u16*)(ws + 12582912);           // 2304*768*2    =  3,538,944
  u16* Wot  = (u16*)(ws + 16121856);           // 768*768*2     =  1,179,648
  u16* qkv  = (u16*)(ws + 17301504);           // 3*96*1024*64*2= 37,748,736
  u16* attn = (u16*)(ws + 55050240);           // 8192*768*2    = 12,582,912

  cvt_x<<<6144, 256, 0, stream>>>(x, Xb, MROWS * EDIM);
  pack_w<<<576, 256, 0, stream>>>(Wq, Wk, Wv, Wo, Wt, Wot);
  gemm_qkv<<<dim3(64, 18), 256, 0, stream>>>(Xb, Wt, bq, bk, bv, qkv);
  attn_kernel<<<dim3(96, 16), 256, 0, stream>>>(qkv, attn);
  gemm_out<<<dim3(64, 6), 256, 0, stream>>>(attn, Wot, bo, out);
}

// Round 3
// 209.608 us; speedup vs baseline: 1.0930x; 1.0930x over previous
//
#include <hip/hip_runtime.h>

typedef unsigned short u16;
typedef __bf16 bf16;
typedef bf16 bf16x8 __attribute__((ext_vector_type(8)));
typedef float f32x4 __attribute__((ext_vector_type(4)));
typedef u16 u16x4 __attribute__((ext_vector_type(4)));
typedef u16 u16x8 __attribute__((ext_vector_type(8)));

#define MROWS 8192      // B*S
#define EDIM 768
#define NQKV 2304       // 3*E
#define NHEAD 12
#define DH 64
#define SEQ 1024
#define BATCH 8
#define BH 96           // BATCH*NHEAD
#define BHSD (BH * SEQ * DH)
#define KIT64 (EDIM / 64)   // 12

#if __has_builtin(__builtin_amdgcn_exp2f)
#define EXP2(x) __builtin_amdgcn_exp2f(x)
#else
#define EXP2(x) exp2f(x)
#endif

// float -> bf16 (native cvt on gfx950, RNE)
__device__ __forceinline__ u16 f2bf(float f) {
  bf16 b = (bf16)f;
  return __builtin_bit_cast(u16, b);
}

// async global->LDS, 16B per lane. LDS dest must be wave-uniform base + lane*16.
__device__ __forceinline__ void gload_lds16(const u16* g, u16* l) {
  __builtin_amdgcn_global_load_lds(
      (const __attribute__((address_space(1))) void*)g,
      (__attribute__((address_space(3))) void*)l, 16, 0, 0);
}

// ---------------- prep kernels ----------------

__global__ void cvt_x(const float* __restrict__ x, u16* __restrict__ xb, int n) {
  int i = (blockIdx.x * blockDim.x + threadIdx.x) * 4;
  if (i >= n) return;
  float4 v = *(const float4*)(x + i);
  u16x4 o;
  o[0] = f2bf(v.x); o[1] = f2bf(v.y); o[2] = f2bf(v.z); o[3] = f2bf(v.w);
  *(u16x4*)(xb + i) = o;
}

// LDS tile-transpose pack. Blocks 0..431: Wt tiles; 432..575: Wot tiles.
// Wt[n][e], n=region*768+h*64+d, equals W_region[h][e][d]. Wot[n][e]=Wo[e][n].
__global__ __launch_bounds__(256) void pack_w(
    const float* __restrict__ Wq, const float* __restrict__ Wk,
    const float* __restrict__ Wv, const float* __restrict__ Wo,
    u16* __restrict__ Wt, u16* __restrict__ Wot) {
  __shared__ float T[64][65];
  int bid = blockIdx.x;
  int tid = threadIdx.x;
  int c = tid & 63, r4 = tid >> 6;    // 4 rows per pass, 16 passes
  if (bid < 432) {
    int region = bid / 144, rem = bid - region * 144;
    int h = rem / 12, e0 = (rem - h * 12) * 64;
    const float* W = region == 0 ? Wq : (region == 1 ? Wk : Wv);
    for (int p = 0; p < 16; p++) {
      int er = r4 + p * 4;
      T[er][c] = W[(size_t)(h * EDIM + e0 + er) * DH + c];   // coalesced read (d=c)
    }
    __syncthreads();
    int nbase = region * EDIM + h * 64;
    for (int p = 0; p < 16; p++) {
      int dr = r4 + p * 4;
      Wt[(size_t)(nbase + dr) * EDIM + e0 + c] = f2bf(T[c][dr]);  // coalesced write (e=c)
    }
  } else {
    bid -= 432;
    int n0 = (bid / 12) * 64, e0 = (bid - (bid / 12) * 12) * 64;
    for (int p = 0; p < 16; p++) {
      int er = r4 + p * 4;
      T[er][c] = Wo[(size_t)(e0 + er) * EDIM + n0 + c];      // coalesced read (n=c)
    }
    __syncthreads();
    for (int p = 0; p < 16; p++) {
      int dr = r4 + p * 4;
      Wot[(size_t)(n0 + dr) * EDIM + e0 + c] = f2bf(T[c][dr]);
    }
  }
}

// ---------------- GEMM core: 128x128 tile, BK=64, global_load_lds staging ----------
// XOR swizzle (zero bank conflicts measured): element [row][c*8+j] lives at
// row*64 + ((c ^ (row&7))*8 + j). global_load_lds writes LDS LINEARLY
// (wave base + lane*16), so the swizzle is applied on the GLOBAL SOURCE
// address (rule #21: linear dest + inverse-swizzled source + swizzled read).
__device__ __forceinline__ void gemm_core64(
    const u16* __restrict__ A, const u16* __restrict__ Bt,
    u16* As, u16* Bs,                 // each 128*64 elements (16 KB)
    int m0, int n0, int tid, f32x4 acc[4][4]) {
  int wv = __builtin_amdgcn_readfirstlane(tid >> 6);
  int lane = tid & 63, quad = lane >> 4, l16 = lane & 15;
  int wm = (wv & 1) * 64, wn = (wv >> 1) * 64;
  int lr = lane >> 3, cpos = lane & 7;       // 8 rows x 8 16B-chunks per wave-instr
  int swcol = (cpos ^ lr) * 8;               // inverse-swizzled source column
  const u16* Ag = A + (size_t)(m0 + wv * 32 + lr) * EDIM + swcol;
  const u16* Bg = Bt + (size_t)(n0 + wv * 32 + lr) * EDIM + swcol;
  u16* Asl = As + (wv * 32 + lr) * 64 + cpos * 8;   // == wave base + lane*16B
  u16* Bsl = Bs + (wv * 32 + lr) * 64 + cpos * 8;

  for (int k = 0; k < KIT64; k++) {
    __syncthreads();                 // previous iter's ds_reads complete before overwrite
    const u16* ak = Ag + k * 64;
    const u16* bk = Bg + k * 64;
#pragma unroll
    for (int q = 0; q < 4; q++) {    // q: 8-row groups; wave covers rows wv*32..wv*32+31
      gload_lds16(ak + q * 8 * EDIM, Asl + q * 512);
      gload_lds16(bk + q * 8 * EDIM, Bsl + q * 512);
    }
    __syncthreads();                 // compiler drains vmcnt(0) here: tile ready
#pragma unroll
    for (int kh = 0; kh < 2; kh++) {
      bf16x8 af[4], bfr[4];
      for (int i = 0; i < 4; i++) {
        int row = wm + i * 16 + l16;
        af[i] = *(const bf16x8*)(As + row * 64 + (((kh * 4 + quad) ^ (row & 7))) * 8);
      }
      for (int j = 0; j < 4; j++) {
        int row = wn + j * 16 + l16;
        bfr[j] = *(const bf16x8*)(Bs + row * 64 + (((kh * 4 + quad) ^ (row & 7))) * 8);
      }
      for (int i = 0; i < 4; i++)
        for (int j = 0; j < 4; j++)
          acc[i][j] = __builtin_amdgcn_mfma_f32_16x16x32_bf16(af[i], bfr[j], acc[i][j], 0, 0, 0);
    }
  }
}

// ---------------- GEMM 1: QKV projection ----------------
// XCD remap: lin%8 = XCD (round-robin dispatch). Each XCD owns 8 contiguous
// m-tiles x all 18 n-tiles -> its 1.5MB A-chunk stays hot in its private L2.
__global__ __launch_bounds__(256, 4) void gemm_qkv(
    const u16* __restrict__ A, const u16* __restrict__ Bt,
    const float* __restrict__ bq, const float* __restrict__ bk, const float* __restrict__ bv,
    u16* __restrict__ qkv) {
  __shared__ __align__(16) u16 As[128 * 64];
  __shared__ __align__(16) u16 Bs[128 * 64];
  int tid = threadIdx.x;
  int wv = tid >> 6, lane = tid & 63, quad = lane >> 4, l16 = lane & 15;
  int wm = (wv & 1) * 64, wn = (wv >> 1) * 64;
  int lin = blockIdx.y * 64 + blockIdx.x;
  int xcd = lin & 7, r8 = lin >> 3;          // r8 in 0..143
  int m0 = (xcd * 8 + (r8 & 7)) * 128;
  int n0 = (r8 >> 3) * 128;                  // 0..17
  f32x4 acc[4][4] = {};
  gemm_core64(A, Bt, As, Bs, m0, n0, tid, acc);

  const float kQscale = 0.18033688011112042f; // (1/8) * log2(e)
  for (int i = 0; i < 4; i++) {
    int row0 = m0 + wm + i * 16 + quad * 4;
    for (int j = 0; j < 4; j++) {
      int n = n0 + wn + j * 16 + l16;
      int region = n / EDIM;
      int hd = n - region * EDIM;
      int h = hd >> 6, d = hd & 63;
      const float* bp = region == 0 ? bq : (region == 1 ? bk : bv);
      float bias = bp[hd];
      float scale = region == 0 ? kQscale : 1.0f;
      for (int r = 0; r < 4; r++) {
        int rr = row0 + r;
        int bb = rr >> 10, s = rr & 1023;
        float val = (acc[i][j][r] + bias) * scale;
        u16 bv16 = f2bf(val);
        int bhh = bb * NHEAD + h;
        if (region < 2) {
          qkv[(size_t)region * BHSD + ((size_t)bhh * SEQ + s) * DH + d] = bv16;
        } else {
          qkv[(size_t)2 * BHSD + ((size_t)bhh * DH + d) * SEQ + s] = bv16;
        }
      }
    }
  }
}

// ---------------- flash attention (no-max softmax, in-register row sums) -------------
// All LDS tiles XOR-swizzled (measured: SQ_LDS_BANK_CONFLICT 7.86M -> 0).
// Row sums accumulate in-register (psum); -2 MFMA, -2 ds_read_b128 per wave/tile.
// XCD remap: each XCD runs one batch's 12 heads x 16 q-tiles (K/V 3MB hot in L2).
// launch_bounds (256,4): (256,6) forced VGPR=40 < the ~44 live values -> 64B/thread
// scratch spill of the prefetch regs (WRITE_SIZE 12288->36864 KiB, +17.5us). Do not
// raise the occupancy floor past the live-register set.
__global__ __launch_bounds__(256, 4) void attn_kernel(const u16* __restrict__ qkv, u16* __restrict__ attn) {
  int lin = blockIdx.y * 96 + blockIdx.x;
  int xcd = lin & 7, rr6 = lin >> 3;         // rr6 in 0..191
  int bh = xcd * 12 + (rr6 >> 4);            // 12 heads per XCD
  int qt = rr6 & 15;
  int b = bh / NHEAD, h = bh - b * NHEAD;
  const u16* Q  = qkv + (size_t)bh * SEQ * DH;
  const u16* K  = qkv + (size_t)(BH + bh) * SEQ * DH;
  const u16* VT = qkv + (size_t)(2 * BH + bh) * SEQ * DH;  // [64][1024]
  int tid = threadIdx.x, wave = tid >> 6, lane = tid & 63, quad = lane >> 4, l16 = lane & 15;
  int q_base = qt * 64 + wave * 16;

  __shared__ u16 Ks[64 * 64];       // [t][d] swizzled
  __shared__ u16 Vts[64 * 64];      // [d][t] swizzled
  __shared__ u16 Ps[4][16 * 64];    // per wave P tile [q][t] swizzled

  bf16x8 qf[2];
  for (int c = 0; c < 2; c++)
    qf[c] = *(const bf16x8*)(Q + (size_t)(q_base + l16) * DH + c * 32 + quad * 8);

  f32x4 o[4] = {};
  float psum[4] = {};   // per-lane partial row sums (cols l16+16k of rows quad*4+r)

  int tr = tid >> 3, cpos = tid & 7;          // staging: rows 0..31 (+32), 8 col-chunks
  int ssw = (cpos ^ (tr & 7)) * 8;            // swizzled chunk pos (same for tr, tr+32)
  u16* KsW0 = Ks + tr * 64 + ssw;
  u16* KsW1 = Ks + (tr + 32) * 64 + ssw;
  u16* VsW0 = Vts + tr * 64 + ssw;
  u16* VsW1 = Vts + (tr + 32) * 64 + ssw;
  int tc8 = cpos * 8;

  // prologue: prefetch tile 0 into registers
  u16x8 kv0 = *(const u16x8*)(K + (size_t)tr * DH + tc8);
  u16x8 kv1 = *(const u16x8*)(K + (size_t)(32 + tr) * DH + tc8);
  u16x8 vv0 = *(const u16x8*)(VT + (size_t)tr * SEQ + tc8);
  u16x8 vv1 = *(const u16x8*)(VT + (size_t)(32 + tr) * SEQ + tc8);

  for (int t0 = 0; t0 < SEQ; t0 += 64) {
    __syncthreads();
    *(u16x8*)KsW0 = kv0;
    *(u16x8*)KsW1 = kv1;
    *(u16x8*)VsW0 = vv0;
    *(u16x8*)VsW1 = vv1;
    __syncthreads();
    if (t0 + 64 < SEQ) {   // prefetch next tile during compute
      kv0 = *(const u16x8*)(K + (size_t)(t0 + 64 + tr) * DH + tc8);
      kv1 = *(const u16x8*)(K + (size_t)(t0 + 96 + tr) * DH + tc8);
      vv0 = *(const u16x8*)(VT + (size_t)tr * SEQ + t0 + 64 + tc8);
      vv1 = *(const u16x8*)(VT + (size_t)(32 + tr) * SEQ + t0 + 64 + tc8);
    }

    // scores + exp2 (logits in log2 domain via Q scale; statistically bounded, no max)
    float p[4][4];
    for (int tc = 0; tc < 4; tc++) {
      int krow = tc * 16 + l16, k7 = l16 & 7;
      bf16x8 kf0 = *(const bf16x8*)(Ks + krow * 64 + ((quad ^ k7) * 8));
      bf16x8 kf1 = *(const bf16x8*)(Ks + krow * 64 + (((4 + quad) ^ k7) * 8));
      f32x4 z = {};
      z = __builtin_amdgcn_mfma_f32_16x16x32_bf16(qf[0], kf0, z, 0, 0, 0);
      z = __builtin_amdgcn_mfma_f32_16x16x32_bf16(qf[1], kf1, z, 0, 0, 0);
      for (int r = 0; r < 4; r++) {
        p[tc][r] = EXP2(z[r]);
        psum[r] += p[tc][r];
      }
    }

    // P: C-layout -> A-layout via per-wave LDS round trip (swizzled)
    u16* P = Ps[wave];
    for (int tc = 0; tc < 4; tc++)
      for (int r = 0; r < 4; r++) {
        int prow = quad * 4 + r;
        int pc = tc * 2 + (l16 >> 3);
        P[prow * 64 + ((pc ^ (prow & 7)) * 8) + (l16 & 7)] = f2bf(p[tc][r]);
      }
    bf16x8 pf[2];
    for (int kc = 0; kc < 2; kc++)
      pf[kc] = *(const bf16x8*)(Ps[wave] + l16 * 64 + (((kc * 4 + quad) ^ (l16 & 7)) * 8));

    for (int n = 0; n < 4; n++) {
      int vrow = n * 16 + l16, v7 = l16 & 7;
      bf16x8 vf0 = *(const bf16x8*)(Vts + vrow * 64 + ((quad ^ v7) * 8));
      bf16x8 vf1 = *(const bf16x8*)(Vts + vrow * 64 + (((4 + quad) ^ v7) * 8));
      o[n] = __builtin_amdgcn_mfma_f32_16x16x32_bf16(pf[0], vf0, o[n], 0, 0, 0);
      o[n] = __builtin_amdgcn_mfma_f32_16x16x32_bf16(pf[1], vf1, o[n], 0, 0, 0);
    }
  }

  // finish row sums: reduce psum across the 16 lanes of each quad-group
  for (int m = 1; m < 16; m <<= 1)
    for (int r = 0; r < 4; r++)
      psum[r] += __shfl_xor(psum[r], m);

  // normalize + store to attn [8192][768] bf16, col = h*64 + d.
  for (int r = 0; r < 4; r++) {
    float inv = 1.0f / psum[r];
    int qrow = q_base + quad * 4 + r;
    size_t rowoff = (size_t)(b * SEQ + qrow) * EDIM + h * DH;
    for (int n = 0; n < 4; n++)
      attn[rowoff + n * 16 + l16] = f2bf(o[n][r] * inv);
  }
}

// ---------------- GEMM 3: output projection ----------------
__global__ __launch_bounds__(256, 4) void gemm_out(
    const u16* __restrict__ A, const u16* __restrict__ Bt,
    const float* __restrict__ bo, float* __restrict__ out) {
  __shared__ __align__(16) u16 As[128 * 64];
  __shared__ __align__(16) u16 Bs[128 * 64];
  int tid = threadIdx.x;
  int wv = tid >> 6, lane = tid & 63, quad = lane >> 4, l16 = lane & 15;
  int wm = (wv & 1) * 64, wn = (wv >> 1) * 64;
  int lin = blockIdx.y * 64 + blockIdx.x;
  int xcd = lin & 7, r8 = lin >> 3;          // r8 in 0..47
  int m0 = (xcd * 8 + (r8 & 7)) * 128;
  int n0 = (r8 >> 3) * 128;                  // 0..5
  f32x4 acc[4][4] = {};
  gemm_core64(A, Bt, As, Bs, m0, n0, tid, acc);

  for (int i = 0; i < 4; i++) {
    int row0 = m0 + wm + i * 16 + quad * 4;
    for (int j = 0; j < 4; j++) {
      int n = n0 + wn + j * 16 + l16;
      float bias = bo[n];
      for (int r = 0; r < 4; r++)
        out[(size_t)(row0 + r) * EDIM + n] = acc[i][j][r] + bias;
    }
  }
}

// ---------------- launch ----------------
extern "C" void kernel_launch(void* const* d_in, const int* in_sizes, int n_in,
                              void* d_out, int out_size, void* d_ws, size_t ws_size,
                              hipStream_t stream) {
  const float* x  = (const float*)d_in[0];
  const float* Wq = (const float*)d_in[1];
  const float* bq = (const float*)d_in[2];
  const float* Wk = (const float*)d_in[3];
  const float* bk = (const float*)d_in[4];
  const float* Wv = (const float*)d_in[5];
  const float* bv = (const float*)d_in[6];
  const float* Wo = (const float*)d_in[7];
  const float* bo = (const float*)d_in[8];
  float* out = (float*)d_out;
  char* ws = (char*)d_ws;

  u16* Xb   = (u16*)(ws);                      // 8192*768*2    = 12,582,912
  u16* Wt   = (u16*)(ws + 12582912);           // 2304*768*2    =  3,538,944
  u16* Wot  = (u16*)(ws + 16121856);           // 768*768*2     =  1,179,648
  u16* qkv  = (u16*)(ws + 17301504);           // 3*96*1024*64*2= 37,748,736
  u16* attn = (u16*)(ws + 55050240);           // 8192*768*2    = 12,582,912

  cvt_x<<<6144, 256, 0, stream>>>(x, Xb, MROWS * EDIM);
  pack_w<<<576, 256, 0, stream>>>(Wq, Wk, Wv, Wo, Wt, Wot);
  gemm_qkv<<<dim3(64, 18), 256, 0, stream>>>(Xb, Wt, bq, bk, bv, qkv);
  attn_kernel<<<dim3(96, 16), 256, 0, stream>>>(qkv, attn);
  gemm_out<<<dim3(64, 6), 256, 0, stream>>>(attn, Wot, bo, out);
}

// Round 4
// 208.185 us; speedup vs baseline: 1.1004x; 1.0068x over previous
//
#include <hip/hip_runtime.h>

typedef unsigned short u16;
typedef __bf16 bf16;
typedef bf16 bf16x8 __attribute__((ext_vector_type(8)));
typedef float f32x4 __attribute__((ext_vector_type(4)));
typedef u16 u16x4 __attribute__((ext_vector_type(4)));
typedef u16 u16x8 __attribute__((ext_vector_type(8)));

#define MROWS 8192      // B*S
#define EDIM 768
#define NQKV 2304       // 3*E
#define NHEAD 12
#define DH 64
#define SEQ 1024
#define BATCH 8
#define BH 96           // BATCH*NHEAD
#define BHSD (BH * SEQ * DH)
#define KIT64 (EDIM / 64)   // 12

#if __has_builtin(__builtin_amdgcn_exp2f)
#define EXP2(x) __builtin_amdgcn_exp2f(x)
#else
#define EXP2(x) exp2f(x)
#endif

// float -> bf16 (native cvt on gfx950, RNE)
__device__ __forceinline__ u16 f2bf(float f) {
  bf16 b = (bf16)f;
  return __builtin_bit_cast(u16, b);
}

// async global->LDS, 16B per lane. LDS dest must be wave-uniform base + lane*16.
__device__ __forceinline__ void gload_lds16(const u16* g, u16* l) {
  __builtin_amdgcn_global_load_lds(
      (const __attribute__((address_space(1))) void*)g,
      (__attribute__((address_space(3))) void*)l, 16, 0, 0);
}

// ---------------- prep kernels ----------------

__global__ void cvt_x(const float* __restrict__ x, u16* __restrict__ xb, int n) {
  int i = (blockIdx.x * blockDim.x + threadIdx.x) * 4;
  if (i >= n) return;
  float4 v = *(const float4*)(x + i);
  u16x4 o;
  o[0] = f2bf(v.x); o[1] = f2bf(v.y); o[2] = f2bf(v.z); o[3] = f2bf(v.w);
  *(u16x4*)(xb + i) = o;
}

// LDS tile-transpose pack. Blocks 0..431: Wt tiles; 432..575: Wot tiles.
// Wt[n][e], n=region*768+h*64+d, equals W_region[h][e][d]. Wot[n][e]=Wo[e][n].
__global__ __launch_bounds__(256) void pack_w(
    const float* __restrict__ Wq, const float* __restrict__ Wk,
    const float* __restrict__ Wv, const float* __restrict__ Wo,
    u16* __restrict__ Wt, u16* __restrict__ Wot) {
  __shared__ float T[64][65];
  int bid = blockIdx.x;
  int tid = threadIdx.x;
  int c = tid & 63, r4 = tid >> 6;    // 4 rows per pass, 16 passes
  if (bid < 432) {
    int region = bid / 144, rem = bid - region * 144;
    int h = rem / 12, e0 = (rem - h * 12) * 64;
    const float* W = region == 0 ? Wq : (region == 1 ? Wk : Wv);
    for (int p = 0; p < 16; p++) {
      int er = r4 + p * 4;
      T[er][c] = W[(size_t)(h * EDIM + e0 + er) * DH + c];   // coalesced read (d=c)
    }
    __syncthreads();
    int nbase = region * EDIM + h * 64;
    for (int p = 0; p < 16; p++) {
      int dr = r4 + p * 4;
      Wt[(size_t)(nbase + dr) * EDIM + e0 + c] = f2bf(T[c][dr]);  // coalesced write (e=c)
    }
  } else {
    bid -= 432;
    int n0 = (bid / 12) * 64, e0 = (bid - (bid / 12) * 12) * 64;
    for (int p = 0; p < 16; p++) {
      int er = r4 + p * 4;
      T[er][c] = Wo[(size_t)(e0 + er) * EDIM + n0 + c];      // coalesced read (n=c)
    }
    __syncthreads();
    for (int p = 0; p < 16; p++) {
      int dr = r4 + p * 4;
      Wot[(size_t)(n0 + dr) * EDIM + e0 + c] = f2bf(T[c][dr]);
    }
  }
}

// ---------------- GEMM core: 128x128 tile, BK=64, global_load_lds staging ----------
// XOR swizzle (zero bank conflicts measured): element [row][c*8+j] lives at
// row*64 + ((c ^ (row&7))*8 + j). global_load_lds writes LDS LINEARLY
// (wave base + lane*16), so the swizzle is applied on the GLOBAL SOURCE
// address (rule #21: linear dest + inverse-swizzled source + swizzled read).
__device__ __forceinline__ void gemm_core64(
    const u16* __restrict__ A, const u16* __restrict__ Bt,
    u16* As, u16* Bs,                 // each 128*64 elements (16 KB)
    int m0, int n0, int tid, f32x4 acc[4][4]) {
  int wv = __builtin_amdgcn_readfirstlane(tid >> 6);
  int lane = tid & 63, quad = lane >> 4, l16 = lane & 15;
  int wm = (wv & 1) * 64, wn = (wv >> 1) * 64;
  int lr = lane >> 3, cpos = lane & 7;       // 8 rows x 8 16B-chunks per wave-instr
  int swcol = (cpos ^ lr) * 8;               // inverse-swizzled source column
  const u16* Ag = A + (size_t)(m0 + wv * 32 + lr) * EDIM + swcol;
  const u16* Bg = Bt + (size_t)(n0 + wv * 32 + lr) * EDIM + swcol;
  u16* Asl = As + (wv * 32 + lr) * 64 + cpos * 8;   // == wave base + lane*16B
  u16* Bsl = Bs + (wv * 32 + lr) * 64 + cpos * 8;

  for (int k = 0; k < KIT64; k++) {
    __syncthreads();                 // previous iter's ds_reads complete before overwrite
    const u16* ak = Ag + k * 64;
    const u16* bk = Bg + k * 64;
#pragma unroll
    for (int q = 0; q < 4; q++) {    // q: 8-row groups; wave covers rows wv*32..wv*32+31
      gload_lds16(ak + q * 8 * EDIM, Asl + q * 512);
      gload_lds16(bk + q * 8 * EDIM, Bsl + q * 512);
    }
    __syncthreads();                 // compiler drains vmcnt(0) here: tile ready
#pragma unroll
    for (int kh = 0; kh < 2; kh++) {
      bf16x8 af[4], bfr[4];
      for (int i = 0; i < 4; i++) {
        int row = wm + i * 16 + l16;
        af[i] = *(const bf16x8*)(As + row * 64 + (((kh * 4 + quad) ^ (row & 7))) * 8);
      }
      for (int j = 0; j < 4; j++) {
        int row = wn + j * 16 + l16;
        bfr[j] = *(const bf16x8*)(Bs + row * 64 + (((kh * 4 + quad) ^ (row & 7))) * 8);
      }
      for (int i = 0; i < 4; i++)
        for (int j = 0; j < 4; j++)
          acc[i][j] = __builtin_amdgcn_mfma_f32_16x16x32_bf16(af[i], bfr[j], acc[i][j], 0, 0, 0);
    }
  }
}

// ---------------- GEMM 1: QKV projection ----------------
// XCD remap: lin%8 = XCD (round-robin dispatch). Each XCD owns 8 contiguous
// m-tiles x all 18 n-tiles -> its 1.5MB A-chunk stays hot in its private L2.
__global__ __launch_bounds__(256, 4) void gemm_qkv(
    const u16* __restrict__ A, const u16* __restrict__ Bt,
    const float* __restrict__ bq, const float* __restrict__ bk, const float* __restrict__ bv,
    u16* __restrict__ qkv) {
  __shared__ __align__(16) u16 As[128 * 64];
  __shared__ __align__(16) u16 Bs[128 * 64];
  int tid = threadIdx.x;
  int wv = tid >> 6, lane = tid & 63, quad = lane >> 4, l16 = lane & 15;
  int wm = (wv & 1) * 64, wn = (wv >> 1) * 64;
  int lin = blockIdx.y * 64 + blockIdx.x;
  int xcd = lin & 7, r8 = lin >> 3;          // r8 in 0..143
  int m0 = (xcd * 8 + (r8 & 7)) * 128;
  int n0 = (r8 >> 3) * 128;                  // 0..17
  f32x4 acc[4][4] = {};
  gemm_core64(A, Bt, As, Bs, m0, n0, tid, acc);

  const float kQscale = 0.18033688011112042f; // (1/8) * log2(e)
  for (int i = 0; i < 4; i++) {
    int row0 = m0 + wm + i * 16 + quad * 4;
    for (int j = 0; j < 4; j++) {
      int n = n0 + wn + j * 16 + l16;
      int region = n / EDIM;
      int hd = n - region * EDIM;
      int h = hd >> 6, d = hd & 63;
      const float* bp = region == 0 ? bq : (region == 1 ? bk : bv);
      float bias = bp[hd];
      float scale = region == 0 ? kQscale : 1.0f;
      for (int r = 0; r < 4; r++) {
        int rr = row0 + r;
        int bb = rr >> 10, s = rr & 1023;
        float val = (acc[i][j][r] + bias) * scale;
        u16 bv16 = f2bf(val);
        int bhh = bb * NHEAD + h;
        if (region < 2) {
          qkv[(size_t)region * BHSD + ((size_t)bhh * SEQ + s) * DH + d] = bv16;
        } else {
          qkv[(size_t)2 * BHSD + ((size_t)bhh * DH + d) * SEQ + s] = bv16;
        }
      }
    }
  }
}

// ---------------- flash attention (no-max softmax, in-register row sums) -------------
// 2-phase async pipeline (T3-minimal): K/V double-buffered in LDS, staged by
// global_load_lds with inverse-swizzled SOURCE addresses (rule #21; zero bank
// conflicts measured with this XOR pattern). ONE barrier per t-tile (was 2):
// at loop top issue async loads for tile t+1 into buf^1, compute tile t from
// buf, then __syncthreads() -- its vmcnt(0) drain certifies tile t+1 landed
// AND all waves finished reading buf. Load latency hides under a full tile of
// MFMA+exp2. No prefetch VGPRs (R2 lesson: spills cost 3x HBM writes).
// T5: s_setprio(1) around MFMA clusters (+4-7% on independent-block attn, m191).
// XCD remap: each XCD runs one batch's 12 heads x 16 q-tiles (K/V hot in L2;
// measured FETCH 43->18.5 MB).
__global__ __launch_bounds__(256, 4) void attn_kernel(const u16* __restrict__ qkv, u16* __restrict__ attn) {
  int lin = blockIdx.y * 96 + blockIdx.x;
  int xcd = lin & 7, rr6 = lin >> 3;         // rr6 in 0..191
  int bh = xcd * 12 + (rr6 >> 4);            // 12 heads per XCD
  int qt = rr6 & 15;
  int b = bh / NHEAD, h = bh - b * NHEAD;
  const u16* Q  = qkv + (size_t)bh * SEQ * DH;
  const u16* K  = qkv + (size_t)(BH + bh) * SEQ * DH;
  const u16* VT = qkv + (size_t)(2 * BH + bh) * SEQ * DH;  // [64][1024]
  int tid = threadIdx.x, wave = tid >> 6, lane = tid & 63, quad = lane >> 4, l16 = lane & 15;
  int q_base = qt * 64 + wave * 16;

  __shared__ __align__(16) u16 Ks[2][64 * 64];   // [t][d] swizzled, double-buffered
  __shared__ __align__(16) u16 Vts[2][64 * 64];  // [d][t] swizzled, double-buffered
  __shared__ __align__(16) u16 Ps[4][16 * 64];   // per wave P tile [q][t] swizzled

  bf16x8 qf[2];
  for (int c = 0; c < 2; c++)
    qf[c] = *(const bf16x8*)(Q + (size_t)(q_base + l16) * DH + c * 32 + quad * 8);

  f32x4 o[4] = {};
  float psum[4] = {};   // per-lane partial row sums (cols l16+16k of rows quad*4+r)

  // staging geometry: 32 rows x 8 16B-chunks per pass, 2 passes (rows +32).
  // LDS dest is linear (wave base + lane*16B); source column pre-swizzled.
  int tr = tid >> 3, cpos = tid & 7;
  int ssw = (cpos ^ (tr & 7)) * 8;            // inverse-swizzled source chunk (u16)
  const u16* Kg0 = K + (size_t)tr * DH + ssw;
  const u16* Kg1 = K + (size_t)(tr + 32) * DH + ssw;
  const u16* Vg0 = VT + (size_t)tr * SEQ + ssw;
  const u16* Vg1 = VT + (size_t)(tr + 32) * SEQ + ssw;
  int dst0 = tr * 64 + cpos * 8;              // bytes: wave*1024 + lane*16
  int dst1 = (tr + 32) * 64 + cpos * 8;

  // prologue: async-stage tile 0 into buffer 0
  gload_lds16(Kg0, Ks[0] + dst0);
  gload_lds16(Kg1, Ks[0] + dst1);
  gload_lds16(Vg0, Vts[0] + dst0);
  gload_lds16(Vg1, Vts[0] + dst1);
  __syncthreads();   // vmcnt(0) drain: tile 0 ready

  int buf = 0;
  for (int t0 = 0; t0 < SEQ; t0 += 64) {
    if (t0 + 64 < SEQ) {   // issue async loads for next tile into the other buffer
      int nb = buf ^ 1;
      gload_lds16(Kg0 + (size_t)(t0 + 64) * DH, Ks[nb] + dst0);
      gload_lds16(Kg1 + (size_t)(t0 + 64) * DH, Ks[nb] + dst1);
      gload_lds16(Vg0 + t0 + 64, Vts[nb] + dst0);
      gload_lds16(Vg1 + t0 + 64, Vts[nb] + dst1);
    }
    const u16* Kb = Ks[buf];
    const u16* Vb = Vts[buf];

    // scores + exp2 (logits in log2 domain via Q scale; statistically bounded, no max)
    float p[4][4];
    __builtin_amdgcn_s_setprio(1);
    for (int tc = 0; tc < 4; tc++) {
      int krow = tc * 16 + l16, k7 = l16 & 7;
      bf16x8 kf0 = *(const bf16x8*)(Kb + krow * 64 + ((quad ^ k7) * 8));
      bf16x8 kf1 = *(const bf16x8*)(Kb + krow * 64 + (((4 + quad) ^ k7) * 8));
      f32x4 z = {};
      z = __builtin_amdgcn_mfma_f32_16x16x32_bf16(qf[0], kf0, z, 0, 0, 0);
      z = __builtin_amdgcn_mfma_f32_16x16x32_bf16(qf[1], kf1, z, 0, 0, 0);
      for (int r = 0; r < 4; r++) {
        p[tc][r] = EXP2(z[r]);
        psum[r] += p[tc][r];
      }
    }
    __builtin_amdgcn_s_setprio(0);

    // P: C-layout -> A-layout via per-wave LDS round trip (swizzled, lgkm-ordered)
    u16* P = Ps[wave];
    for (int tc = 0; tc < 4; tc++)
      for (int r = 0; r < 4; r++) {
        int prow = quad * 4 + r;
        int pc = tc * 2 + (l16 >> 3);
        P[prow * 64 + ((pc ^ (prow & 7)) * 8) + (l16 & 7)] = f2bf(p[tc][r]);
      }
    bf16x8 pf[2];
    for (int kc = 0; kc < 2; kc++)
      pf[kc] = *(const bf16x8*)(Ps[wave] + l16 * 64 + (((kc * 4 + quad) ^ (l16 & 7)) * 8));

    __builtin_amdgcn_s_setprio(1);
    for (int n = 0; n < 4; n++) {
      int vrow = n * 16 + l16, v7 = l16 & 7;
      bf16x8 vf0 = *(const bf16x8*)(Vb + vrow * 64 + ((quad ^ v7) * 8));
      bf16x8 vf1 = *(const bf16x8*)(Vb + vrow * 64 + (((4 + quad) ^ v7) * 8));
      o[n] = __builtin_amdgcn_mfma_f32_16x16x32_bf16(pf[0], vf0, o[n], 0, 0, 0);
      o[n] = __builtin_amdgcn_mfma_f32_16x16x32_bf16(pf[1], vf1, o[n], 0, 0, 0);
    }
    __builtin_amdgcn_s_setprio(0);

    __syncthreads();   // drains vmcnt(0): next tile landed; all waves done with buf
    buf ^= 1;
  }

  // finish row sums: reduce psum across the 16 lanes of each quad-group
  for (int m = 1; m < 16; m <<= 1)
    for (int r = 0; r < 4; r++)
      psum[r] += __shfl_xor(psum[r], m);

  // normalize + store to attn [8192][768] bf16, col = h*64 + d.
  for (int r = 0; r < 4; r++) {
    float inv = 1.0f / psum[r];
    int qrow = q_base + quad * 4 + r;
    size_t rowoff = (size_t)(b * SEQ + qrow) * EDIM + h * DH;
    for (int n = 0; n < 4; n++)
      attn[rowoff + n * 16 + l16] = f2bf(o[n][r] * inv);
  }
}

// ---------------- GEMM 3: output projection ----------------
__global__ __launch_bounds__(256, 4) void gemm_out(
    const u16* __restrict__ A, const u16* __restrict__ Bt,
    const float* __restrict__ bo, float* __restrict__ out) {
  __shared__ __align__(16) u16 As[128 * 64];
  __shared__ __align__(16) u16 Bs[128 * 64];
  int tid = threadIdx.x;
  int wv = tid >> 6, lane = tid & 63, quad = lane >> 4, l16 = lane & 15;
  int wm = (wv & 1) * 64, wn = (wv >> 1) * 64;
  int lin = blockIdx.y * 64 + blockIdx.x;
  int xcd = lin & 7, r8 = lin >> 3;          // r8 in 0..47
  int m0 = (xcd * 8 + (r8 & 7)) * 128;
  int n0 = (r8 >> 3) * 128;                  // 0..5
  f32x4 acc[4][4] = {};
  gemm_core64(A, Bt, As, Bs, m0, n0, tid, acc);

  for (int i = 0; i < 4; i++) {
    int row0 = m0 + wm + i * 16 + quad * 4;
    for (int j = 0; j < 4; j++) {
      int n = n0 + wn + j * 16 + l16;
      float bias = bo[n];
      for (int r = 0; r < 4; r++)
        out[(size_t)(row0 + r) * EDIM + n] = acc[i][j][r] + bias;
    }
  }
}

// ---------------- launch ----------------
extern "C" void kernel_launch(void* const* d_in, const int* in_sizes, int n_in,
                              void* d_out, int out_size, void* d_ws, size_t ws_size,
                              hipStream_t stream) {
  const float* x  = (const float*)d_in[0];
  const float* Wq = (const float*)d_in[1];
  const float* bq = (const float*)d_in[2];
  const float* Wk = (const float*)d_in[3];
  const float* bk = (const float*)d_in[4];
  const float* Wv = (const float*)d_in[5];
  const float* bv = (const float*)d_in[6];
  const float* Wo = (const float*)d_in[7];
  const float* bo = (const float*)d_in[8];
  float* out = (float*)d_out;
  char* ws = (char*)d_ws;

  u16* Xb   = (u16*)(ws);                      // 8192*768*2    = 12,582,912
  u16* Wt   = (u16*)(ws + 12582912);           // 2304*768*2    =  3,538,944
  u16* Wot  = (u16*)(ws + 16121856);           // 768*768*2     =  1,179,648
  u16* qkv  = (u16*)(ws + 17301504);           // 3*96*1024*64*2= 37,748,736
  u16* attn = (u16*)(ws + 55050240);           // 8192*768*2    = 12,582,912

  cvt_x<<<6144, 256, 0, stream>>>(x, Xb, MROWS * EDIM);
  pack_w<<<576, 256, 0, stream>>>(Wq, Wk, Wv, Wo, Wt, Wot);
  gemm_qkv<<<dim3(64, 18), 256, 0, stream>>>(Xb, Wt, bq, bk, bv, qkv);
  attn_kernel<<<dim3(96, 16), 256, 0, stream>>>(qkv, attn);
  gemm_out<<<dim3(64, 6), 256, 0, stream>>>(attn, Wot, bo, out);
}